// Round 4
// baseline (9665.805 us; speedup 1.0000x reference)
//
#include <hip/hip_runtime.h>
#include <hip/hip_cooperative_groups.h>
#include <math.h>

#define BB   64
#define TT   128
#define HH   1024
#define DIN  2048
#define G4   4096
#define MALL 8192   // B*T
#define NANS 1000

typedef __attribute__((ext_vector_type(8))) short bf16x8;
typedef __attribute__((ext_vector_type(4))) float f32x4;

__device__ __forceinline__ float sigmoidf_(float x) { return 1.0f / (1.0f + expf(-x)); }

__device__ __forceinline__ unsigned short f2bf(float f) {
  unsigned u = __float_as_uint(f);
  u = (u + 0x7fff + ((u >> 16) & 1)) >> 16;   // RNE
  return (unsigned short)u;
}
__device__ __forceinline__ float bf2f(unsigned short h) {
  return __uint_as_float(((unsigned)h) << 16);
}
__device__ __forceinline__ f32x4 mfma16(bf16x8 a, bf16x8 b, f32x4 c) {
  return __builtin_amdgcn_mfma_f32_16x16x32_bf16(a, b, c, 0, 0, 0);
}

// ---------------------------------------------------------------------------
// conversion kernels
// ---------------------------------------------------------------------------
__global__ __launch_bounds__(256) void concat_cast(
    const float* __restrict__ a, const float* __restrict__ b,
    unsigned short* __restrict__ o, int rshift, long total)
{
  long idx = ((long)blockIdx.x * 256 + threadIdx.x) * 4;
  if (idx >= total) return;
  int row = (int)(idx >> rshift);
  int col = (int)(idx & ((1L << rshift) - 1));
  int half = 1 << (rshift - 1);
  const float* s = (col < half) ? (a + (size_t)row * half + col)
                                : (b + (size_t)row * half + col - half);
  float4 v = *(const float4*)s;
  ushort4 ov;
  ov.x = f2bf(v.x); ov.y = f2bf(v.y); ov.z = f2bf(v.z); ov.w = f2bf(v.w);
  *(ushort4*)(o + idx) = ov;
}

__global__ __launch_bounds__(256) void cast_bf16(
    const float* __restrict__ s, unsigned short* __restrict__ o, long n)
{
  long idx = ((long)blockIdx.x * 256 + threadIdx.x) * 4;
  if (idx >= n) return;
  float4 v = *(const float4*)(s + idx);
  ushort4 ov;
  ov.x = f2bf(v.x); ov.y = f2bf(v.y); ov.z = f2bf(v.z); ov.w = f2bf(v.w);
  *(ushort4*)(o + idx) = ov;
}

__global__ __launch_bounds__(256) void cvt_wp1(
    const float* __restrict__ Wp1, unsigned short* __restrict__ o)
{
  int idx = blockIdx.x * 256 + threadIdx.x;    // 262144
  int n = idx >> 10, k = idx & 1023;
  o[idx] = f2bf(Wp1[(size_t)k * 256 + n]);
}

__global__ __launch_bounds__(256) void cvt_wp2(
    const float* __restrict__ Wp2, unsigned short* __restrict__ o)
{
  int idx = blockIdx.x * 256 + threadIdx.x;    // 262144
  int n = idx >> 8, k = idx & 255;
  o[idx] = f2bf(n < NANS ? Wp2[(size_t)k * NANS + n] : 0.f);
}

__global__ __launch_bounds__(256) void zero_f4(float4* __restrict__ p)
{
  p[blockIdx.x * 256 + threadIdx.x] = make_float4(0.f, 0.f, 0.f, 0.f);
}

// ---------------------------------------------------------------------------
// Templated bf16 MFMA GEMM (unchanged from round 3): C = A @ W^T (+bias)(relu)
// ---------------------------------------------------------------------------
template<int OUT_BF16, int RELU, int PERM>
__global__ __launch_bounds__(256) void mfma_gemm(
    const unsigned short* __restrict__ A,   // [M][K] bf16
    const unsigned short* __restrict__ W,   // [N][K] bf16
    const float* __restrict__ bias,         // [nvalid]
    void* __restrict__ Cout,
    int M, int N, int K, int ldc, int nvalid)
{
  __shared__ __align__(16) unsigned short As[128 * 72];
  __shared__ __align__(16) unsigned short Bs[128 * 72];
  const int t = threadIdx.x;
  const int n0 = blockIdx.x * 128, m0 = blockIdx.y * 128;
  const int w = t >> 6, lane = t & 63, lr = lane & 15, q = lane >> 4;
  const int wn = (w & 1) * 64, wm = (w >> 1) * 64;
  f32x4 acc[4][4] = {};
  for (int k0 = 0; k0 < K; k0 += 64) {
    #pragma unroll
    for (int s = 0; s < 4; s++) {
      int ci = s * 256 + t;
      int row = ci >> 3, c = ci & 7;
      bf16x8 va = *(const bf16x8*)(A + (size_t)(m0 + row) * K + k0 + c * 8);
      *(bf16x8*)(As + row * 72 + c * 8) = va;
      bf16x8 vb = *(const bf16x8*)(W + (size_t)(n0 + row) * K + k0 + c * 8);
      *(bf16x8*)(Bs + row * 72 + c * 8) = vb;
    }
    __syncthreads();
    #pragma unroll
    for (int kk = 0; kk < 2; kk++) {
      bf16x8 a[4], b[4];
      #pragma unroll
      for (int mt = 0; mt < 4; mt++)
        a[mt] = *(const bf16x8*)(As + (wm + mt * 16 + lr) * 72 + kk * 32 + q * 8);
      #pragma unroll
      for (int nt = 0; nt < 4; nt++)
        b[nt] = *(const bf16x8*)(Bs + (wn + nt * 16 + lr) * 72 + kk * 32 + q * 8);
      #pragma unroll
      for (int mt = 0; mt < 4; mt++)
        #pragma unroll
        for (int nt = 0; nt < 4; nt++)
          acc[mt][nt] = mfma16(a[mt], b[nt], acc[mt][nt]);
    }
    __syncthreads();
  }
  #pragma unroll
  for (int mt = 0; mt < 4; mt++)
    #pragma unroll
    for (int nt = 0; nt < 4; nt++)
      #pragma unroll
      for (int r = 0; r < 4; r++) {
        int row = m0 + wm + mt * 16 + q * 4 + r;
        int col = n0 + wn + nt * 16 + lr;
        if (col < nvalid) {
          float v = acc[mt][nt][r] + bias[col];
          if (RELU) v = fmaxf(v, 0.f);
          if (PERM) row = ((row & 127) << 6) | (row >> 7);
          if (OUT_BF16)
            ((unsigned short*)Cout)[(size_t)row * ldc + col] = f2bf(v);
          else
            ((float*)Cout)[(size_t)row * ldc + col] = v;
        }
      }
}

// ---------------------------------------------------------------------------
// Persistent cooperative LSTM loop. 512 blocks x 256 thr (2 blocks/CU).
// Blocks 0..255   (A): layer-1 cell for timestep p   (weights Whh1, K=1024)
// Blocks 256..511 (B): layer-2 cell for timestep p-1 (weights [Wih2|Whh2], K=2048)
// Per phase both read only state written in earlier phases -> ONE grid.sync.
// Weights + cell state (c) live in REGISTERS for the entire loop.
// hbuf = [2][64][2048] bf16 (h1|h2), ping-pong by phase parity. Must be zeroed.
// ---------------------------------------------------------------------------
__global__ __launch_bounds__(256, 2) void lstm_loop(
    const unsigned short* __restrict__ Whh1b,   // [4096][1024]
    const unsigned short* __restrict__ W2cat,   // [4096][2048]
    const unsigned short* __restrict__ gxb,     // [T*64][4096] (t-major)
    const float* __restrict__ b2,
    unsigned short* __restrict__ hbuf,          // [2][64][2048], pre-zeroed
    unsigned short* __restrict__ lob)           // [8192][1024]
{
  cooperative_groups::grid_group grid = cooperative_groups::this_grid();
  __shared__ float red[4][64][17];
  const int t = threadIdx.x;
  const int w = t >> 6, lane = t & 63, lr = lane & 15, q = lane >> 4;
  const bool isA = (blockIdx.x < 256);
  const int j0 = (isA ? blockIdx.x : blockIdx.x - 256) * 4;
  const int g0 = lr >> 2, u0 = lr & 3;              // weight row = g0*1024 + j0+u0
  const int cm = t >> 2, cu = t & 3, ju = j0 + cu;  // cell-phase mapping

  // --- one-time: weights + bias into registers ---
  bf16x8 wreg[16];
  float b2r[4] = {0.f, 0.f, 0.f, 0.f};
  if (isA) {
    const unsigned short* wp =
        Whh1b + (size_t)(g0 * 1024 + j0 + u0) * 1024 + w * 256 + q * 8;
    #pragma unroll
    for (int ks = 0; ks < 8; ks++) wreg[ks] = *(const bf16x8*)(wp + ks * 32);
  } else {
    const unsigned short* wp =
        W2cat + (size_t)(g0 * 1024 + j0 + u0) * 2048 + w * 512 + q * 8;
    #pragma unroll
    for (int ks = 0; ks < 16; ks++) wreg[ks] = *(const bf16x8*)(wp + ks * 32);
    #pragma unroll
    for (int gg = 0; gg < 4; gg++) b2r[gg] = b2[gg * 1024 + ju];
  }
  float creg = 0.f;   // c1 (A-blocks) / c2 (B-blocks), persists across phases

  for (int p = 0; p <= TT; p++) {
    const unsigned short* hprev = hbuf + (size_t)((p + 1) & 1) * 131072;
    unsigned short*       hc    = hbuf + (size_t)(p & 1) * 131072;
    if (isA) {
      if (p < TT) {
        // prefetch gx (consumed after barrier; overlaps MFMA section)
        const unsigned short* gp = gxb + ((size_t)(p << 6) + cm) * 4096 + ju;
        unsigned short gi = gp[0], gf = gp[1024], gg2 = gp[2048], go = gp[3072];
        f32x4 acc[4] = {};
        const unsigned short* hb = hprev + w * 256 + q * 8;
        #pragma unroll
        for (int ks = 0; ks < 8; ks++)
          #pragma unroll
          for (int mt = 0; mt < 4; mt++) {
            bf16x8 af = *(const bf16x8*)(hb + (size_t)(mt * 16 + lr) * 2048 + ks * 32);
            acc[mt] = mfma16(af, wreg[ks], acc[mt]);
          }
        #pragma unroll
        for (int mt = 0; mt < 4; mt++)
          #pragma unroll
          for (int r = 0; r < 4; r++)
            red[w][mt * 16 + q * 4 + r][lr] = acc[mt][r];
        __syncthreads();
        float s[4];
        #pragma unroll
        for (int gg = 0; gg < 4; gg++)
          s[gg] = red[0][cm][gg * 4 + cu] + red[1][cm][gg * 4 + cu]
                + red[2][cm][gg * 4 + cu] + red[3][cm][gg * 4 + cu];
        s[0] += bf2f(gi); s[1] += bf2f(gf); s[2] += bf2f(gg2); s[3] += bf2f(go);
        float i_ = sigmoidf_(s[0]), f_ = sigmoidf_(s[1]);
        float g_ = tanhf(s[2]), o_ = sigmoidf_(s[3]);
        creg = f_ * creg + i_ * g_;
        hc[(size_t)cm * 2048 + ju] = f2bf(o_ * tanhf(creg));
      }
    } else {
      if (p >= 1) {
        f32x4 acc[4] = {};
        const unsigned short* hb = hprev + w * 512 + q * 8;
        #pragma unroll
        for (int ks = 0; ks < 16; ks++)
          #pragma unroll
          for (int mt = 0; mt < 4; mt++) {
            bf16x8 af = *(const bf16x8*)(hb + (size_t)(mt * 16 + lr) * 2048 + ks * 32);
            acc[mt] = mfma16(af, wreg[ks], acc[mt]);
          }
        #pragma unroll
        for (int mt = 0; mt < 4; mt++)
          #pragma unroll
          for (int r = 0; r < 4; r++)
            red[w][mt * 16 + q * 4 + r][lr] = acc[mt][r];
        __syncthreads();
        float s[4];
        #pragma unroll
        for (int gg = 0; gg < 4; gg++)
          s[gg] = red[0][cm][gg * 4 + cu] + red[1][cm][gg * 4 + cu]
                + red[2][cm][gg * 4 + cu] + red[3][cm][gg * 4 + cu] + b2r[gg];
        float i_ = sigmoidf_(s[0]), f_ = sigmoidf_(s[1]);
        float g_ = tanhf(s[2]), o_ = sigmoidf_(s[3]);
        creg = f_ * creg + i_ * g_;
        float h2v = o_ * tanhf(creg);
        hc[(size_t)cm * 2048 + 1024 + ju] = f2bf(h2v);
        float h1v = bf2f(hprev[(size_t)cm * 2048 + ju]);   // h1 of SAME timestep
        lob[((size_t)(cm << 7) + (p - 1)) * 1024 + ju] = f2bf(h1v + h2v);
      }
    }
    if (p < TT) grid.sync();
  }
}

// ---------------------------------------------------------------------------
// Fallback per-step kernels (round-3, proven) — used only if cooperative
// launch is rejected. c1/c2 live in global for this path.
// ---------------------------------------------------------------------------
__global__ __launch_bounds__(256) void lstm_stepA(
    const unsigned short* __restrict__ hprev, const unsigned short* __restrict__ Wb,
    const unsigned short* __restrict__ gxb, int tstep,
    unsigned short* hcur, float* __restrict__ c1)
{
  __shared__ float red[4][64][17];
  const int t = threadIdx.x;
  const int w = t >> 6, lane = t & 63, lr = lane & 15, q = lane >> 4;
  const int j0 = blockIdx.x * 4;
  {
    const int g = lr >> 2, u0 = lr & 3;
    const unsigned short* wp = Wb + (size_t)(g * 1024 + j0 + u0) * 1024;
    f32x4 acc[4] = {};
    const int kb = w * 256;
    #pragma unroll
    for (int ks = 0; ks < 8; ks++) {
      int k = kb + ks * 32 + q * 8;
      bf16x8 bfrag = *(const bf16x8*)(wp + k);
      #pragma unroll
      for (int mt = 0; mt < 4; mt++) {
        bf16x8 afrag = *(const bf16x8*)(hprev + (size_t)(mt * 16 + lr) * 2048 + k);
        acc[mt] = mfma16(afrag, bfrag, acc[mt]);
      }
    }
    #pragma unroll
    for (int mt = 0; mt < 4; mt++)
      #pragma unroll
      for (int r = 0; r < 4; r++)
        red[w][mt * 16 + q * 4 + r][lr] = acc[mt][r];
  }
  __syncthreads();
  const int m = t >> 2, u = t & 3;
  float s[4];
  #pragma unroll
  for (int g = 0; g < 4; g++)
    s[g] = red[0][m][g * 4 + u] + red[1][m][g * 4 + u]
         + red[2][m][g * 4 + u] + red[3][m][g * 4 + u];
  const unsigned short* gp = gxb + (size_t)((tstep << 6) + m) * 4096 + j0 + u;
  s[0] += bf2f(gp[0]); s[1] += bf2f(gp[1024]);
  s[2] += bf2f(gp[2048]); s[3] += bf2f(gp[3072]);
  const int ju = j0 + u;
  float i_ = sigmoidf_(s[0]), f_ = sigmoidf_(s[1]);
  float g_ = tanhf(s[2]), o_ = sigmoidf_(s[3]);
  float c = f_ * c1[m * 1024 + ju] + i_ * g_;
  c1[m * 1024 + ju] = c;
  hcur[(size_t)m * 2048 + ju] = f2bf(o_ * tanhf(c));
}

__global__ __launch_bounds__(256) void lstm_stepB(
    const unsigned short* __restrict__ hprev, unsigned short* hcur,
    const unsigned short* __restrict__ W2, const float* __restrict__ b2,
    int tstep, float* __restrict__ c2, unsigned short* __restrict__ lob)
{
  __shared__ float red[4][64][17];
  const int t = threadIdx.x;
  const int w = t >> 6, lane = t & 63, lr = lane & 15, q = lane >> 4;
  const int j0 = blockIdx.x * 4;
  {
    const int g = lr >> 2, u0 = lr & 3;
    const unsigned short* wp = W2 + (size_t)(g * 1024 + j0 + u0) * 2048;
    f32x4 acc[4] = {};
    const int kb = w * 512;
    #pragma unroll
    for (int ks = 0; ks < 16; ks++) {
      int k = kb + ks * 32 + q * 8;
      bf16x8 bfrag = *(const bf16x8*)(wp + k);
      const unsigned short* hsrc = (k < 1024) ? hcur : hprev;
      #pragma unroll
      for (int mt = 0; mt < 4; mt++) {
        bf16x8 afrag = *(const bf16x8*)(hsrc + (size_t)(mt * 16 + lr) * 2048 + k);
        acc[mt] = mfma16(afrag, bfrag, acc[mt]);
      }
    }
    #pragma unroll
    for (int mt = 0; mt < 4; mt++)
      #pragma unroll
      for (int r = 0; r < 4; r++)
        red[w][mt * 16 + q * 4 + r][lr] = acc[mt][r];
  }
  __syncthreads();
  const int m = t >> 2, u = t & 3;
  const int ju = j0 + u;
  float s[4];
  #pragma unroll
  for (int g = 0; g < 4; g++)
    s[g] = red[0][m][g * 4 + u] + red[1][m][g * 4 + u]
         + red[2][m][g * 4 + u] + red[3][m][g * 4 + u]
         + b2[g * 1024 + ju];
  float i_ = sigmoidf_(s[0]), f_ = sigmoidf_(s[1]);
  float g_ = tanhf(s[2]), o_ = sigmoidf_(s[3]);
  float c = f_ * c2[m * 1024 + ju] + i_ * g_;
  c2[m * 1024 + ju] = c;
  float h2v = o_ * tanhf(c);
  hcur[(size_t)m * 2048 + 1024 + ju] = f2bf(h2v);
  float h1v = bf2f(hcur[(size_t)m * 2048 + ju]);
  lob[(size_t)((m << 7) + tstep) * 1024 + ju] = f2bf(h1v + h2v);
}

// ---------------------------------------------------------------------------
__global__ __launch_bounds__(256) void softmax_k(float* __restrict__ out)
{
  __shared__ float smax[4];
  __shared__ float ssum[4];
  const int m = blockIdx.x;
  const int t = threadIdx.x;
  const int lane = t & 63, wid = t >> 6;
  const bool act = (t < 250);
  float x[4] = {0.f, 0.f, 0.f, 0.f};
  if (act) *(float4*)x = *(const float4*)(out + (size_t)m * NANS + t * 4);
  float v = act ? fmaxf(fmaxf(x[0], x[1]), fmaxf(x[2], x[3])) : -1e30f;
  #pragma unroll
  for (int o = 32; o > 0; o >>= 1) v = fmaxf(v, __shfl_down(v, o));
  if (lane == 0) smax[wid] = v;
  __syncthreads();
  const float mx = fmaxf(fmaxf(smax[0], smax[1]), fmaxf(smax[2], smax[3]));
  float e[4] = {0.f, 0.f, 0.f, 0.f};
  float s = 0.f;
  if (act) {
    e[0] = expf(x[0] - mx); e[1] = expf(x[1] - mx);
    e[2] = expf(x[2] - mx); e[3] = expf(x[3] - mx);
    s = (e[0] + e[1]) + (e[2] + e[3]);
  }
  #pragma unroll
  for (int o = 32; o > 0; o >>= 1) s += __shfl_down(s, o);
  if (lane == 0) ssum[wid] = s;
  __syncthreads();
  const float inv = 1.0f / (((ssum[0] + ssum[1]) + (ssum[2] + ssum[3])));
  if (act) {
    float4 o4 = make_float4(e[0] * inv, e[1] * inv, e[2] * inv, e[3] * inv);
    *(float4*)(out + (size_t)m * NANS + t * 4) = o4;
  }
}

// ---------------------------------------------------------------------------
extern "C" void kernel_launch(void* const* d_in, const int* in_sizes, int n_in,
                              void* d_out, int out_size, void* d_ws, size_t ws_size,
                              hipStream_t stream)
{
  const float* d1   = (const float*)d_in[0];
  const float* d2   = (const float*)d_in[1];
  const float* Wih1 = (const float*)d_in[2];
  const float* Whh1 = (const float*)d_in[3];
  const float* b1   = (const float*)d_in[4];
  const float* Wih2 = (const float*)d_in[5];
  const float* Whh2 = (const float*)d_in[6];
  const float* b2   = (const float*)d_in[7];
  const float* Wp1  = (const float*)d_in[8];
  const float* bp1  = (const float*)d_in[9];
  const float* Wp2  = (const float*)d_in[10];
  const float* bp2  = (const float*)d_in[11];
  float* out = (float*)d_out;

  // workspace layout (bytes)
  unsigned char* p = (unsigned char*)d_ws;
  unsigned short* gxb   = (unsigned short*)p;  p += 67108864;  // [T*64][4096]
  unsigned short* jb    = (unsigned short*)p;  p += 33554432;  // [8192][2048]
  unsigned short* Wb1   = (unsigned short*)p;  p += 16777216;  // [4096][2048]
  unsigned short* W2cat = (unsigned short*)p;  p += 16777216;  // [4096][2048]
  unsigned short* Whh1b = (unsigned short*)p;  p += 8388608;   // [4096][1024]
  unsigned short* lob   = (unsigned short*)p;  p += 16777216;  // [8192][1024]
  unsigned short* hidb  = (unsigned short*)p;  p += 4194304;   // [8192][256]
  unsigned short* Wp1t  = (unsigned short*)p;  p += 524288;    // [256][1024]
  unsigned short* Wp2t  = (unsigned short*)p;  p += 524288;    // [1024][256]
  unsigned short* hbuf  = (unsigned short*)p;  p += 524288;    // [2][64][2048]
  float*          c1    = (float*)p;           p += 262144;    // fallback only
  float*          c2    = (float*)p;           p += 262144;    // fallback only
  if (ws_size < (size_t)(p - (unsigned char*)d_ws)) return;

  // ---- convert inputs/weights to bf16 ----
  concat_cast<<<16384, 256, 0, stream>>>(d1, d2, jb, 11, 16777216L);
  cast_bf16<<<8192, 256, 0, stream>>>(Wih1, Wb1, 8388608L);
  cast_bf16<<<4096, 256, 0, stream>>>(Whh1, Whh1b, 4194304L);
  concat_cast<<<8192, 256, 0, stream>>>(Wih2, Whh2, W2cat, 11, 8388608L);
  cvt_wp1<<<1024, 256, 0, stream>>>(Wp1, Wp1t);
  cvt_wp2<<<1024, 256, 0, stream>>>(Wp2, Wp2t);
  zero_f4<<<256, 256, 0, stream>>>((float4*)hbuf);   // hbuf + c1 + c2 (1 MiB)

  // ---- gx = joint @ Wih1^T + b1 (t-major permuted, bf16) ----
  mfma_gemm<1, 0, 1><<<dim3(32, 64), 256, 0, stream>>>(
      jb, Wb1, b1, gxb, MALL, G4, DIN, G4, G4);

  // ---- recurrent loop: persistent cooperative kernel ----
  {
    void* args[] = {(void*)&Whh1b, (void*)&W2cat, (void*)&gxb, (void*)&b2,
                    (void*)&hbuf, (void*)&lob};
    hipError_t ce = hipLaunchCooperativeKernel((void*)lstm_loop, dim3(512),
                                               dim3(256), args, 0, stream);
    if (ce != hipSuccess) {
      // fallback: proven per-step loop (H0=hbuf, H1=hbuf+131072)
      unsigned short* H0 = hbuf;
      unsigned short* H1 = hbuf + 131072;
      for (int t = 0; t < TT; t++) {
        unsigned short* hp = (t & 1) ? H1 : H0;
        unsigned short* hc = (t & 1) ? H0 : H1;
        lstm_stepA<<<256, 256, 0, stream>>>(hp, Whh1b, gxb, t, hc, c1);
        lstm_stepB<<<256, 256, 0, stream>>>(hp, hc, W2cat, b2, t, c2, lob);
      }
    }
  }

  // ---- predict MLP + softmax ----
  mfma_gemm<1, 1, 0><<<dim3(2, 64), 256, 0, stream>>>(
      lob, Wp1t, bp1, hidb, MALL, 256, 1024, 256, 256);
  mfma_gemm<0, 0, 0><<<dim3(8, 64), 256, 0, stream>>>(
      hidb, Wp2t, bp2, out, MALL, 1024, 256, NANS, NANS);
  softmax_k<<<MALL, 256, 0, stream>>>(out);
}

// Round 5
// 2802.652 us; speedup vs baseline: 3.4488x; 3.4488x over previous
//
#include <hip/hip_runtime.h>
#include <math.h>

#define BB   64
#define TT   128
#define HH   1024
#define DIN  2048
#define G4   4096
#define MALL 8192   // B*T
#define NANS 1000

typedef __attribute__((ext_vector_type(8))) short bf16x8;
typedef __attribute__((ext_vector_type(4))) float f32x4;

__device__ __forceinline__ float sigmoidf_(float x) { return 1.0f / (1.0f + expf(-x)); }

__device__ __forceinline__ unsigned short f2bf(float f) {
  unsigned u = __float_as_uint(f);
  u = (u + 0x7fff + ((u >> 16) & 1)) >> 16;   // RNE
  return (unsigned short)u;
}
__device__ __forceinline__ float bf2f(unsigned short h) {
  return __uint_as_float(((unsigned)h) << 16);
}
__device__ __forceinline__ f32x4 mfma16(bf16x8 a, bf16x8 b, f32x4 c) {
  return __builtin_amdgcn_mfma_f32_16x16x32_bf16(a, b, c, 0, 0, 0);
}

// ---------------------------------------------------------------------------
// conversion kernels
// ---------------------------------------------------------------------------
__global__ __launch_bounds__(256) void concat_cast(
    const float* __restrict__ a, const float* __restrict__ b,
    unsigned short* __restrict__ o, int rshift, long total)
{
  long idx = ((long)blockIdx.x * 256 + threadIdx.x) * 4;
  if (idx >= total) return;
  int row = (int)(idx >> rshift);
  int col = (int)(idx & ((1L << rshift) - 1));
  int half = 1 << (rshift - 1);
  const float* s = (col < half) ? (a + (size_t)row * half + col)
                                : (b + (size_t)row * half + col - half);
  float4 v = *(const float4*)s;
  ushort4 ov;
  ov.x = f2bf(v.x); ov.y = f2bf(v.y); ov.z = f2bf(v.z); ov.w = f2bf(v.w);
  *(ushort4*)(o + idx) = ov;
}

__global__ __launch_bounds__(256) void cast_bf16(
    const float* __restrict__ s, unsigned short* __restrict__ o, long n)
{
  long idx = ((long)blockIdx.x * 256 + threadIdx.x) * 4;
  if (idx >= n) return;
  float4 v = *(const float4*)(s + idx);
  ushort4 ov;
  ov.x = f2bf(v.x); ov.y = f2bf(v.y); ov.z = f2bf(v.z); ov.w = f2bf(v.w);
  *(ushort4*)(o + idx) = ov;
}

__global__ __launch_bounds__(256) void cvt_wp1(
    const float* __restrict__ Wp1, unsigned short* __restrict__ o)
{
  int idx = blockIdx.x * 256 + threadIdx.x;    // 262144
  int n = idx >> 10, k = idx & 1023;
  o[idx] = f2bf(Wp1[(size_t)k * 256 + n]);
}

__global__ __launch_bounds__(256) void cvt_wp2(
    const float* __restrict__ Wp2, unsigned short* __restrict__ o)
{
  int idx = blockIdx.x * 256 + threadIdx.x;    // 262144
  int n = idx >> 8, k = idx & 255;
  o[idx] = f2bf(n < NANS ? Wp2[(size_t)k * NANS + n] : 0.f);
}

__global__ __launch_bounds__(256) void zero_f4(float4* __restrict__ p)
{
  p[blockIdx.x * 256 + threadIdx.x] = make_float4(0.f, 0.f, 0.f, 0.f);
}

// ---------------------------------------------------------------------------
// Templated bf16 MFMA GEMM: C = A @ W^T (+bias)(relu). 128x128 tile, BK=64.
// ---------------------------------------------------------------------------
template<int OUT_BF16, int RELU, int PERM>
__global__ __launch_bounds__(256) void mfma_gemm(
    const unsigned short* __restrict__ A,   // [M][K] bf16
    const unsigned short* __restrict__ W,   // [N][K] bf16
    const float* __restrict__ bias,         // [nvalid]
    void* __restrict__ Cout,
    int M, int N, int K, int ldc, int nvalid)
{
  __shared__ __align__(16) unsigned short As[128 * 72];
  __shared__ __align__(16) unsigned short Bs[128 * 72];
  const int t = threadIdx.x;
  const int n0 = blockIdx.x * 128, m0 = blockIdx.y * 128;
  const int w = t >> 6, lane = t & 63, lr = lane & 15, q = lane >> 4;
  const int wn = (w & 1) * 64, wm = (w >> 1) * 64;
  f32x4 acc[4][4] = {};
  for (int k0 = 0; k0 < K; k0 += 64) {
    #pragma unroll
    for (int s = 0; s < 4; s++) {
      int ci = s * 256 + t;
      int row = ci >> 3, c = ci & 7;
      bf16x8 va = *(const bf16x8*)(A + (size_t)(m0 + row) * K + k0 + c * 8);
      *(bf16x8*)(As + row * 72 + c * 8) = va;
      bf16x8 vb = *(const bf16x8*)(W + (size_t)(n0 + row) * K + k0 + c * 8);
      *(bf16x8*)(Bs + row * 72 + c * 8) = vb;
    }
    __syncthreads();
    #pragma unroll
    for (int kk = 0; kk < 2; kk++) {
      bf16x8 a[4], b[4];
      #pragma unroll
      for (int mt = 0; mt < 4; mt++)
        a[mt] = *(const bf16x8*)(As + (wm + mt * 16 + lr) * 72 + kk * 32 + q * 8);
      #pragma unroll
      for (int nt = 0; nt < 4; nt++)
        b[nt] = *(const bf16x8*)(Bs + (wn + nt * 16 + lr) * 72 + kk * 32 + q * 8);
      #pragma unroll
      for (int mt = 0; mt < 4; mt++)
        #pragma unroll
        for (int nt = 0; nt < 4; nt++)
          acc[mt][nt] = mfma16(a[mt], b[nt], acc[mt][nt]);
    }
    __syncthreads();
  }
  #pragma unroll
  for (int mt = 0; mt < 4; mt++)
    #pragma unroll
    for (int nt = 0; nt < 4; nt++)
      #pragma unroll
      for (int r = 0; r < 4; r++) {
        int row = m0 + wm + mt * 16 + q * 4 + r;
        int col = n0 + wn + nt * 16 + lr;
        if (col < nvalid) {
          float v = acc[mt][nt][r] + bias[col];
          if (RELU) v = fmaxf(v, 0.f);
          if (PERM) row = ((row & 127) << 6) | (row >> 7);
          if (OUT_BF16)
            ((unsigned short*)Cout)[(size_t)row * ldc + col] = f2bf(v);
          else
            ((float*)Cout)[(size_t)row * ldc + col] = v;
        }
      }
}

// ---------------------------------------------------------------------------
// lstm_phase: ONE launch per phase p (kernel boundary = grid barrier; CG
// grid.sync measured 72 us/phase on gfx950 -- round-4 post-mortem).
// Blocks 0..255   (A): layer-1 cell for t=p    (skip at p==TT)
// Blocks 256..511 (B): layer-2 cell for t=p-1  (skip at p==0)
// Independent: A(p) needs h1(p-1); B(p-1) needs h1(p-1), h2(p-2) -- all
// written in phases <= p-1.
// hbuf = [2][64][2048] bf16 (h1|h2 halves), slot = t&1; hprev = slot (p-1)&1.
// A writes h1-half of slot p&1; B writes h2-half of slot (p-1)&1... NOTE:
// B(p-1) writes h2(p-1) into slot (p-1)&1 h2-half == hprev h2-half, which is
// read NEXT phase by B(p); A only reads hprev h1-half -> no conflict.
// ---------------------------------------------------------------------------
__global__ __launch_bounds__(256) void lstm_phase(
    const unsigned short* __restrict__ Whh1b,   // [4096][1024]
    const unsigned short* __restrict__ W2cat,   // [4096][2048]
    const unsigned short* __restrict__ gxb,     // [T*64][4096] (t-major)
    const float* __restrict__ b2,
    int p,
    unsigned short* __restrict__ hbuf,          // [2][64][2048]
    float* __restrict__ c1, float* __restrict__ c2,
    unsigned short* __restrict__ lob)           // [8192][1024]
{
  __shared__ float red[4][64][17];
  const int t = threadIdx.x;
  const int w = t >> 6, lane = t & 63, lr = lane & 15, q = lane >> 4;
  const bool isA = (blockIdx.x < 256);
  const int j0 = (isA ? blockIdx.x : blockIdx.x - 256) * 4;
  const int g0 = lr >> 2, u0 = lr & 3;
  const int cm = t >> 2, cu = t & 3, ju = j0 + cu;
  const unsigned short* hprev = hbuf + (size_t)((p + 1) & 1) * 131072;
  unsigned short*       hc    = hbuf + (size_t)(p & 1) * 131072;

  if (isA) {
    if (p == TT) return;
    // gx prefetch (scalar, 4x2B; consumed after the MFMA section)
    const unsigned short* gp = gxb + ((size_t)(p << 6) + cm) * 4096 + ju;
    unsigned short gi = gp[0], gf = gp[1024], gg2 = gp[2048], go = gp[3072];
    {
      const unsigned short* wp =
          Whh1b + (size_t)(g0 * 1024 + j0 + u0) * 1024 + w * 256 + q * 8;
      const unsigned short* hb = hprev + w * 256 + q * 8;
      f32x4 acc[4] = {};
      #pragma unroll
      for (int ks = 0; ks < 8; ks++) {
        bf16x8 bfrag = *(const bf16x8*)(wp + ks * 32);
        #pragma unroll
        for (int mt = 0; mt < 4; mt++) {
          bf16x8 af = *(const bf16x8*)(hb + (size_t)(mt * 16 + lr) * 2048 + ks * 32);
          acc[mt] = mfma16(af, bfrag, acc[mt]);
        }
      }
      #pragma unroll
      for (int mt = 0; mt < 4; mt++)
        #pragma unroll
        for (int r = 0; r < 4; r++)
          red[w][mt * 16 + q * 4 + r][lr] = acc[mt][r];
    }
    __syncthreads();
    float s[4];
    #pragma unroll
    for (int gg = 0; gg < 4; gg++)
      s[gg] = red[0][cm][gg * 4 + cu] + red[1][cm][gg * 4 + cu]
            + red[2][cm][gg * 4 + cu] + red[3][cm][gg * 4 + cu];
    s[0] += bf2f(gi); s[1] += bf2f(gf); s[2] += bf2f(gg2); s[3] += bf2f(go);
    float i_ = sigmoidf_(s[0]), f_ = sigmoidf_(s[1]);
    float g_ = tanhf(s[2]), o_ = sigmoidf_(s[3]);
    float c = f_ * c1[cm * 1024 + ju] + i_ * g_;
    c1[cm * 1024 + ju] = c;
    hc[(size_t)cm * 2048 + ju] = f2bf(o_ * tanhf(c));
  } else {
    if (p == 0) return;
    {
      const unsigned short* wp =
          W2cat + (size_t)(g0 * 1024 + j0 + u0) * 2048 + w * 512 + q * 8;
      const unsigned short* hb = hprev + w * 512 + q * 8;
      f32x4 acc[4] = {};
      #pragma unroll
      for (int ks = 0; ks < 16; ks++) {
        bf16x8 bfrag = *(const bf16x8*)(wp + ks * 32);
        #pragma unroll
        for (int mt = 0; mt < 4; mt++) {
          bf16x8 af = *(const bf16x8*)(hb + (size_t)(mt * 16 + lr) * 2048 + ks * 32);
          acc[mt] = mfma16(af, bfrag, acc[mt]);
        }
      }
      #pragma unroll
      for (int mt = 0; mt < 4; mt++)
        #pragma unroll
        for (int r = 0; r < 4; r++)
          red[w][mt * 16 + q * 4 + r][lr] = acc[mt][r];
    }
    __syncthreads();
    float s[4];
    #pragma unroll
    for (int gg = 0; gg < 4; gg++)
      s[gg] = red[0][cm][gg * 4 + cu] + red[1][cm][gg * 4 + cu]
            + red[2][cm][gg * 4 + cu] + red[3][cm][gg * 4 + cu]
            + b2[gg * 1024 + ju];
    float i_ = sigmoidf_(s[0]), f_ = sigmoidf_(s[1]);
    float g_ = tanhf(s[2]), o_ = sigmoidf_(s[3]);
    float c = f_ * c2[cm * 1024 + ju] + i_ * g_;
    c2[cm * 1024 + ju] = c;
    float h2v = o_ * tanhf(c);
    // h2(p-1) -> slot (p-1)&1 h2-half  (== hprev buffer)
    ((unsigned short*)hprev)[(size_t)cm * 2048 + 1024 + ju] = f2bf(h2v);
    float h1v = bf2f(hprev[(size_t)cm * 2048 + ju]);   // h1(p-1)
    lob[((size_t)(cm << 7) + (p - 1)) * 1024 + ju] = f2bf(h1v + h2v);
  }
}

// ---------------------------------------------------------------------------
__global__ __launch_bounds__(256) void softmax_k(float* __restrict__ out)
{
  __shared__ float smax[4];
  __shared__ float ssum[4];
  const int m = blockIdx.x;
  const int t = threadIdx.x;
  const int lane = t & 63, wid = t >> 6;
  const bool act = (t < 250);
  float x[4] = {0.f, 0.f, 0.f, 0.f};
  if (act) *(float4*)x = *(const float4*)(out + (size_t)m * NANS + t * 4);
  float v = act ? fmaxf(fmaxf(x[0], x[1]), fmaxf(x[2], x[3])) : -1e30f;
  #pragma unroll
  for (int o = 32; o > 0; o >>= 1) v = fmaxf(v, __shfl_down(v, o));
  if (lane == 0) smax[wid] = v;
  __syncthreads();
  const float mx = fmaxf(fmaxf(smax[0], smax[1]), fmaxf(smax[2], smax[3]));
  float e[4] = {0.f, 0.f, 0.f, 0.f};
  float s = 0.f;
  if (act) {
    e[0] = expf(x[0] - mx); e[1] = expf(x[1] - mx);
    e[2] = expf(x[2] - mx); e[3] = expf(x[3] - mx);
    s = (e[0] + e[1]) + (e[2] + e[3]);
  }
  #pragma unroll
  for (int o = 32; o > 0; o >>= 1) s += __shfl_down(s, o);
  if (lane == 0) ssum[wid] = s;
  __syncthreads();
  const float inv = 1.0f / (((ssum[0] + ssum[1]) + (ssum[2] + ssum[3])));
  if (act) {
    float4 o4 = make_float4(e[0] * inv, e[1] * inv, e[2] * inv, e[3] * inv);
    *(float4*)(out + (size_t)m * NANS + t * 4) = o4;
  }
}

// ---------------------------------------------------------------------------
extern "C" void kernel_launch(void* const* d_in, const int* in_sizes, int n_in,
                              void* d_out, int out_size, void* d_ws, size_t ws_size,
                              hipStream_t stream)
{
  const float* d1   = (const float*)d_in[0];
  const float* d2   = (const float*)d_in[1];
  const float* Wih1 = (const float*)d_in[2];
  const float* Whh1 = (const float*)d_in[3];
  const float* b1   = (const float*)d_in[4];
  const float* Wih2 = (const float*)d_in[5];
  const float* Whh2 = (const float*)d_in[6];
  const float* b2   = (const float*)d_in[7];
  const float* Wp1  = (const float*)d_in[8];
  const float* bp1  = (const float*)d_in[9];
  const float* Wp2  = (const float*)d_in[10];
  const float* bp2  = (const float*)d_in[11];
  float* out = (float*)d_out;

  // workspace layout (bytes)
  unsigned char* p = (unsigned char*)d_ws;
  unsigned short* gxb   = (unsigned short*)p;  p += 67108864;  // [T*64][4096]
  unsigned short* jb    = (unsigned short*)p;  p += 33554432;  // [8192][2048]
  unsigned short* Wb1   = (unsigned short*)p;  p += 16777216;  // [4096][2048]
  unsigned short* W2cat = (unsigned short*)p;  p += 16777216;  // [4096][2048]
  unsigned short* Whh1b = (unsigned short*)p;  p += 8388608;   // [4096][1024]
  unsigned short* lob   = (unsigned short*)p;  p += 16777216;  // [8192][1024]
  unsigned short* hidb  = (unsigned short*)p;  p += 4194304;   // [8192][256]
  unsigned short* Wp1t  = (unsigned short*)p;  p += 524288;    // [256][1024]
  unsigned short* Wp2t  = (unsigned short*)p;  p += 524288;    // [1024][256]
  unsigned short* hbuf  = (unsigned short*)p;  p += 524288;    // [2][64][2048]
  float*          c1    = (float*)p;           p += 262144;
  float*          c2    = (float*)p;           p += 262144;
  if (ws_size < (size_t)(p - (unsigned char*)d_ws)) return;

  // ---- convert inputs/weights to bf16 ----
  concat_cast<<<16384, 256, 0, stream>>>(d1, d2, jb, 11, 16777216L);
  cast_bf16<<<8192, 256, 0, stream>>>(Wih1, Wb1, 8388608L);
  cast_bf16<<<4096, 256, 0, stream>>>(Whh1, Whh1b, 4194304L);
  concat_cast<<<8192, 256, 0, stream>>>(Wih2, Whh2, W2cat, 11, 8388608L);
  cvt_wp1<<<1024, 256, 0, stream>>>(Wp1, Wp1t);
  cvt_wp2<<<1024, 256, 0, stream>>>(Wp2, Wp2t);
  zero_f4<<<256, 256, 0, stream>>>((float4*)hbuf);   // hbuf + c1 + c2 (1 MiB)

  // ---- gx = joint @ Wih1^T + b1 (t-major permuted, bf16) ----
  mfma_gemm<1, 0, 1><<<dim3(32, 64), 256, 0, stream>>>(
      jb, Wb1, b1, gxb, MALL, G4, DIN, G4, G4);

  // ---- recurrent loop: one launch per phase (kernel boundary = barrier) ----
  for (int ph = 0; ph <= TT; ph++)
    lstm_phase<<<512, 256, 0, stream>>>(Whh1b, W2cat, gxb, b2, ph,
                                        hbuf, c1, c2, lob);

  // ---- predict MLP + softmax ----
  mfma_gemm<1, 1, 0><<<dim3(2, 64), 256, 0, stream>>>(
      lob, Wp1t, bp1, hidb, MALL, 256, 1024, 256, 256);
  mfma_gemm<0, 0, 0><<<dim3(8, 64), 256, 0, stream>>>(
      hidb, Wp2t, bp2, out, MALL, 1024, 256, NANS, NANS);
  softmax_k<<<MALL, 256, 0, stream>>>(out);
}